// Round 6
// baseline (1597.795 us; speedup 1.0000x reference)
//
#include <hip/hip_runtime.h>
#include <hip/hip_bf16.h>

typedef __attribute__((ext_vector_type(8))) short short8;
typedef __attribute__((ext_vector_type(4))) float f32x4;

// pack 8 fp32 -> 8 bf16 (RNE) as one short8 (4 VGPRs)
__device__ __forceinline__ short8 pack8(const f32x4& a, const f32x4& b) {
    union { __hip_bfloat162 h[4]; short8 s; } u;
    u.h[0] = __float22bfloat162_rn(make_float2(a[0], a[1]));
    u.h[1] = __float22bfloat162_rn(make_float2(a[2], a[3]));
    u.h[2] = __float22bfloat162_rn(make_float2(b[0], b[1]));
    u.h[3] = __float22bfloat162_rn(make_float2(b[2], b[3]));
    return u.s;
}

// Granule swizzle (involution, store AND load): injects k-oct bits into bank
// bits so staging ds_write_b128 spreads; reads stay conflict-free (verified
// r4/r5: SQ_LDS_BANK_CONFLICT ~4e5 total).
__device__ __forceinline__ int swz(int g) { return g ^ (((g >> 4) & 3) << 1); }

// ---- 4-wave 128x128/wave variant of the r4 8-phase counted-vmcnt template ----
// Grid: 4096 = 512 km x 4 mt x 2 nt. Block: 256 thr = 4 waves (2M x 2N).
// Tile: BM=256 x BN=256 x BK=64. LDS: 2 buf x (A 32KB | B 32KB) = 128KB.
// Per wave: output 128x128, acc[8][8] f32x4 = 256 VGPR -> 1 wave/SIMD.
// Phase p of K-tile kt: kk=p>>1, mhalf=p&1:
//   ds_read av[4] (+bv[8] on even p) of tile kt [cur buf]
//   vmcnt(8) -> cvt+4 ds_write (quarter type p of tile kt+1, staged 2 phases ago)
//   issue 8 loads of quarter type (p+2)&3 -> lgkmcnt(0); barrier; 32 MFMA.
// Race audit: writes target buf[(kt+1)&1] != read buf[kt&1]; every barrier is
// preceded by lgkmcnt(0), so all LDS ops (incl. staging writes) are visible
// before any wave proceeds; reads of tile kt+1 start only after (kt,3)'s barrier.
// vmcnt: batches are 8 loads/phase; quarter written at phase g was issued at
// g-2, with only g-1's 8 loads younger -> vmcnt(8) (FIFO retire). Tail: last
// issue at (6,1); (6,2) waits (6,0)-batch via vmcnt(8); (6,3) vmcnt(0).
#define PHASE(P, KTV, SET, DOW, DOI, VM)                                          \
  do {                                                                            \
    const char* rb_ = smem + ((KTV) & 1) * 65536;                                 \
    _Pragma("unroll") for (int ii = 0; ii < 4; ++ii)                              \
        av[ii] = *(const short8*)(rb_ +                                           \
            (((wm * 8 + ((P) & 1) * 4 + ii) * 2 + ((P) >> 1)) << 10) + rdo);      \
    if (((P) & 1) == 0) {                                                         \
      _Pragma("unroll") for (int pp = 0; pp < 8; ++pp)                            \
          bv[pp] = *(const short8*)(rb_ + 32768 +                                 \
              (((wn * 8 + pp) * 2 + ((P) >> 1)) << 10) + rdo);                    \
    }                                                                             \
    if (DOW) {                                                                    \
      asm volatile("s_waitcnt vmcnt(" #VM ")" ::: "memory");                      \
      short8 w0_ = pack8(SET[0], SET[1]);                                         \
      short8 w1_ = pack8(SET[2], SET[3]);                                         \
      short8 w2_ = pack8(SET[4], SET[5]);                                         \
      short8 w3_ = pack8(SET[6], SET[7]);                                         \
      char* wdst_ = smem + (((KTV) + 1) & 1) * 65536 +                            \
                    (((P) >= 2) ? 32768 : 0) + (((P) & 1) * 16384) + wfrag;       \
      *(short8*)wdst_ = w0_;                                                      \
      *(short8*)(wdst_ + 1024) = w1_;                                             \
      *(short8*)(wdst_ + 8192) = w2_;                                             \
      *(short8*)(wdst_ + 9216) = w3_;                                             \
    }                                                                             \
    if (DOI) {                                                                    \
      const float* isrc_ = (((P) >= 2) ? (As + ((KTV) + 2) * 64)                  \
                                       : (Bs + ((KTV) + 1) * 64)) +               \
                           (((P) & 1) ? 65536 : 0);                               \
      SET[0] = *(const f32x4*)isrc_;                                              \
      SET[1] = *(const f32x4*)(isrc_ + 4);                                        \
      SET[2] = *(const f32x4*)(isrc_ + 32);                                       \
      SET[3] = *(const f32x4*)(isrc_ + 36);                                       \
      SET[4] = *(const f32x4*)(isrc_ + 32768);                                    \
      SET[5] = *(const f32x4*)(isrc_ + 32772);                                    \
      SET[6] = *(const f32x4*)(isrc_ + 32800);                                    \
      SET[7] = *(const f32x4*)(isrc_ + 32804);                                    \
    }                                                                             \
    asm volatile("s_waitcnt lgkmcnt(0)" ::: "memory");                            \
    __builtin_amdgcn_sched_barrier(0);                                            \
    __builtin_amdgcn_s_barrier();                                                 \
    __builtin_amdgcn_s_setprio(1);                                                \
    _Pragma("unroll") for (int ii = 0; ii < 4; ++ii)                              \
        _Pragma("unroll") for (int pp = 0; pp < 8; ++pp)                          \
            acc[((P) & 1) * 4 + ii][pp] = __builtin_amdgcn_mfma_f32_16x16x32_bf16(\
                av[ii], bv[pp], acc[((P) & 1) * 4 + ii][pp], 0, 0, 0);            \
    __builtin_amdgcn_s_setprio(0);                                                \
    __builtin_amdgcn_sched_barrier(0);                                            \
  } while (0)

#define PRO_WRITE(TT, ROFF)                                                       \
  do {                                                                            \
    short8 a_ = pack8(TT[0], TT[1]);                                              \
    short8 b_ = pack8(TT[2], TT[3]);                                              \
    char* d_ = smem + (ROFF) + wfrag;                                             \
    *(short8*)d_ = a_;                                                            \
    *(short8*)(d_ + 1024) = b_;                                                   \
  } while (0)

__global__ __launch_bounds__(256, 1)
void ens_mlp_kernel(const float* __restrict__ X,
                    const float* __restrict__ W1,
                    const float* __restrict__ B1,
                    const float* __restrict__ W2,
                    const float* __restrict__ B2,
                    float* __restrict__ out)
{
    extern __shared__ char smem[];
    const int t    = threadIdx.x;
    const int lane = t & 63;
    const int wv   = t >> 6;      // 0..3
    const int wm   = wv >> 1;     // 0..1
    const int wn   = wv & 1;      // 0..1

    // XCD-aware decode: 8 blocks of the same km adjacent on one XCD.
    const int bb  = blockIdx.x;
    const int xcd = bb & 7;
    const int j   = bb >> 3;
    const int km  = xcd * 64 + (j >> 3);   // 0..511
    const int sub = j & 7;
    const int mt  = sub >> 1;              // 0..3 (256-row batch tile)
    const int nt  = sub & 1;               // 0..1 (256-col n half)

    const float* __restrict__ W1k = W1 + (size_t)km * (512 * 512);

    // staging identity: thread handles rows {lr, lr+64} (per half), k-octs {c, c+4}
    const int lr = t >> 2;                 // 0..63
    const int c  = t & 3;
    const float* As = X   + (size_t)(mt * 256 + lr) * 512 + c * 8;
    const float* Bs = W1k + (size_t)(nt * 256 + lr) * 512 + c * 8;
    const int wfrag = ((lr >> 4) << 11) + (swz((c << 4) | (lr & 15)) << 4);
    const int rdo   = swz(lane) << 4;      // fragment read offset (logical=lane)

    // ---- prologue: stage full tile 0 (counted drains), prefetch A(tile1) ----
    f32x4 s0[8], s1[8];
    {
        f32x4 t0[4], t1[4], t2[4], t3[4], t4[4], t5[4], t6[4], t7[4];
        const float* q;
        q = As;          t0[0]=*(const f32x4*)q; t0[1]=*(const f32x4*)(q+4); t0[2]=*(const f32x4*)(q+32); t0[3]=*(const f32x4*)(q+36);
        q = As + 32768;  t1[0]=*(const f32x4*)q; t1[1]=*(const f32x4*)(q+4); t1[2]=*(const f32x4*)(q+32); t1[3]=*(const f32x4*)(q+36);
        q = As + 65536;  t2[0]=*(const f32x4*)q; t2[1]=*(const f32x4*)(q+4); t2[2]=*(const f32x4*)(q+32); t2[3]=*(const f32x4*)(q+36);
        q = As + 98304;  t3[0]=*(const f32x4*)q; t3[1]=*(const f32x4*)(q+4); t3[2]=*(const f32x4*)(q+32); t3[3]=*(const f32x4*)(q+36);
        q = Bs;          t4[0]=*(const f32x4*)q; t4[1]=*(const f32x4*)(q+4); t4[2]=*(const f32x4*)(q+32); t4[3]=*(const f32x4*)(q+36);
        q = Bs + 32768;  t5[0]=*(const f32x4*)q; t5[1]=*(const f32x4*)(q+4); t5[2]=*(const f32x4*)(q+32); t5[3]=*(const f32x4*)(q+36);
        q = Bs + 65536;  t6[0]=*(const f32x4*)q; t6[1]=*(const f32x4*)(q+4); t6[2]=*(const f32x4*)(q+32); t6[3]=*(const f32x4*)(q+36);
        q = Bs + 98304;  t7[0]=*(const f32x4*)q; t7[1]=*(const f32x4*)(q+4); t7[2]=*(const f32x4*)(q+32); t7[3]=*(const f32x4*)(q+36);
        asm volatile("s_waitcnt vmcnt(28)" ::: "memory"); PRO_WRITE(t0, 0);
        asm volatile("s_waitcnt vmcnt(24)" ::: "memory"); PRO_WRITE(t1, 8192);
        asm volatile("s_waitcnt vmcnt(20)" ::: "memory"); PRO_WRITE(t2, 16384);
        asm volatile("s_waitcnt vmcnt(16)" ::: "memory"); PRO_WRITE(t3, 24576);
        asm volatile("s_waitcnt vmcnt(12)" ::: "memory"); PRO_WRITE(t4, 32768);
        asm volatile("s_waitcnt vmcnt(8)"  ::: "memory"); PRO_WRITE(t5, 40960);
        asm volatile("s_waitcnt vmcnt(4)"  ::: "memory"); PRO_WRITE(t6, 49152);
        asm volatile("s_waitcnt vmcnt(0)"  ::: "memory"); PRO_WRITE(t7, 57344);
        // prefetch tile1: A half0 -> s0, A half1 -> s1 (rows lr and lr+64 each)
        q = As + 64;
        s0[0]=*(const f32x4*)q;         s0[1]=*(const f32x4*)(q+4);
        s0[2]=*(const f32x4*)(q+32);    s0[3]=*(const f32x4*)(q+36);
        s0[4]=*(const f32x4*)(q+32768); s0[5]=*(const f32x4*)(q+32772);
        s0[6]=*(const f32x4*)(q+32800); s0[7]=*(const f32x4*)(q+32804);
        q = As + 64 + 65536;
        s1[0]=*(const f32x4*)q;         s1[1]=*(const f32x4*)(q+4);
        s1[2]=*(const f32x4*)(q+32);    s1[3]=*(const f32x4*)(q+36);
        s1[4]=*(const f32x4*)(q+32768); s1[5]=*(const f32x4*)(q+32772);
        s1[6]=*(const f32x4*)(q+32800); s1[7]=*(const f32x4*)(q+32804);
        asm volatile("s_waitcnt lgkmcnt(0)" ::: "memory");
        __builtin_amdgcn_sched_barrier(0);
        __builtin_amdgcn_s_barrier();
    }

    f32x4 acc[8][8];
#pragma unroll
    for (int i = 0; i < 8; ++i)
#pragma unroll
        for (int p = 0; p < 8; ++p)
            acc[i][p] = (f32x4)0.0f;

    short8 av[4], bv[8];

#pragma unroll 1
    for (int kt = 0; kt < 6; ++kt) {
        PHASE(0, kt, s0, true, true, 8);
        PHASE(1, kt, s1, true, true, 8);
        PHASE(2, kt, s0, true, true, 8);
        PHASE(3, kt, s1, true, true, 8);
    }
    // kt=6: last issues are B0/B1 of tile 7 at p=0,1
    PHASE(0, 6, s0, true, true, 8);
    PHASE(1, 6, s1, true, true, 8);
    PHASE(2, 6, s0, true, false, 8);
    PHASE(3, 6, s1, true, false, 0);
    // kt=7: compute only
    PHASE(0, 7, s0, false, false, 0);
    PHASE(1, 7, s1, false, false, 0);
    PHASE(2, 7, s0, false, false, 0);
    PHASE(3, 7, s1, false, false, 0);

    // ---- fused epilogue: partial over this block's 256 n-cols ----
    const int nc = lane & 15;
    const int kq = lane >> 4;
    float b1v[8], w2v[8];
#pragma unroll
    for (int pp = 0; pp < 8; ++pp) {
        int n = nt * 256 + (wn * 8 + pp) * 16 + nc;
        b1v[pp] = B1[km * 512 + n];
        w2v[pp] = W2[km * 512 + n];
    }

    float* lout = (float*)smem;   // [256 rows][2 wn]; all LDS reads drained pre-barrier
#pragma unroll
    for (int i = 0; i < 8; ++i) {
#pragma unroll
        for (int r = 0; r < 4; ++r) {
            float s = 0.f;
#pragma unroll
            for (int pp = 0; pp < 8; ++pp) {
                float h = acc[i][pp][r] + b1v[pp];
                h = h > 0.f ? h : 0.f;
                s += h * w2v[pp];
            }
#pragma unroll
            for (int d = 1; d < 16; d <<= 1)
                s += __shfl_xor(s, d, 64);
            if (nc == 0) {
                int row = wm * 128 + i * 16 + kq * 4 + r;
                lout[row * 2 + wn] = s;
            }
        }
    }
    __syncthreads();
    {
        float s = lout[t * 2 + 0] + lout[t * 2 + 1];
        if (nt == 0) s += B2[km];
        int b = mt * 256 + t;
        // out[b, e, o] with k = o*E + e  ->  flat b*512 + (km%8)*64 + (km/8)
        atomicAdd(out + (size_t)b * 512 + (km & 7) * 64 + (km >> 3), s);
    }
}

extern "C" void kernel_launch(void* const* d_in, const int* in_sizes, int n_in,
                              void* d_out, int out_size, void* d_ws, size_t ws_size,
                              hipStream_t stream) {
    const float* X  = (const float*)d_in[0];
    const float* W1 = (const float*)d_in[1];
    const float* B1 = (const float*)d_in[2];
    const float* W2 = (const float*)d_in[3];
    const float* B2 = (const float*)d_in[4];
    float* out = (float*)d_out;

    hipMemsetAsync(out, 0, (size_t)out_size * sizeof(float), stream);
    ens_mlp_kernel<<<dim3(4096), dim3(256), 131072, stream>>>(X, W1, B1, W2, B2, out);
}

// Round 7
// 428.200 us; speedup vs baseline: 3.7314x; 3.7314x over previous
//
#include <hip/hip_runtime.h>
#include <hip/hip_bf16.h>

typedef __attribute__((ext_vector_type(8))) short short8;
typedef __attribute__((ext_vector_type(4))) float f32x4;

// pack 8 fp32 -> 8 bf16 (RNE) as one short8 (4 VGPRs)
__device__ __forceinline__ short8 pack8(const f32x4& a, const f32x4& b) {
    union { __hip_bfloat162 h[4]; short8 s; } u;
    u.h[0] = __float22bfloat162_rn(make_float2(a[0], a[1]));
    u.h[1] = __float22bfloat162_rn(make_float2(a[2], a[3]));
    u.h[2] = __float22bfloat162_rn(make_float2(b[0], b[1]));
    u.h[3] = __float22bfloat162_rn(make_float2(b[2], b[3]));
    return u.s;
}

// Granule swizzle (involution, store AND load) — r2/r4-proven: staging
// ds_write_b128 spreads across banks, fragment reads stay conflict-free
// (measured SQ_LDS_BANK_CONFLICT ~4e5 total).
__device__ __forceinline__ int swz(int g) { return g ^ (((g >> 4) & 3) << 4 >> 3); }
// NOTE: keep EXACT r4 form below; the line above is not used.
__device__ __forceinline__ int swz4(int g) { return g ^ (((g >> 4) & 3) << 1); }

// ---- r4 maps + ONE barrier per K-tile (free-running tile body) ----
// Grid: 4096 = 512 km x 4 mt x 2 nt. Block: 512 thr = 8 waves (2M x 4N).
// Tile: BM=256 x BN=256 x BK=64. Wave: 128x64, acc[8][4] f32x4 = 128 regs.
// LDS: 2 buf x (A 32KB | B 32KB) = 128KB. 8 K-tiles.
// Per K-tile kt (buf rb=kt&1, wb=buf^1):
//   issue 8 loads (B batch of kt+1) -> kk0: 12 ds_read + 32 MFMA
//   vmcnt(0) -> cvt+4 ds_write (B) -> issue 8 loads (A batch)
//   kk1: 12 ds_read + 32 MFMA -> vmcnt(0) -> cvt+4 ds_write (A)
//   lgkmcnt(0); barrier.      (tile 7: compute only, no barrier)
// Race audit: wb = buffer read during kt-1; all waves drained their reads
// (lgkmcnt(0)) before kt-1's barrier, so writes during kt are safe. Reads of
// tile kt+1 start only after kt's barrier, which follows everyone's writes.
// vmcnt(0): exactly one 8-load batch outstanding at each wait (issued ~1 kk
// earlier). Staging set reused A/B -> 32-reg peak; total ~240/wave, no spill.

#define ISSUE(S, BASE, KT1)                                                   \
  do {                                                                        \
    const float* q_ = (BASE) + (KT1) * 64;                                    \
    S[0] = *(const f32x4*)q_;          S[1] = *(const f32x4*)(q_ + 4);        \
    S[2] = *(const f32x4*)(q_ + 32);   S[3] = *(const f32x4*)(q_ + 36);       \
    const float* q2_ = q_ + 65536;                                            \
    S[4] = *(const f32x4*)q2_;         S[5] = *(const f32x4*)(q2_ + 4);       \
    S[6] = *(const f32x4*)(q2_ + 32);  S[7] = *(const f32x4*)(q2_ + 36);      \
  } while (0)

#define WRITEB(S, WB, OPOFF)                                                  \
  do {                                                                        \
    char* d0_ = (WB) + (OPOFF) + wfrag;                                       \
    *(short8*)d0_ = pack8(S[0], S[1]);                                        \
    *(short8*)(d0_ + 1024) = pack8(S[2], S[3]);                               \
    char* d1_ = d0_ + 16384;                                                  \
    *(short8*)d1_ = pack8(S[4], S[5]);                                        \
    *(short8*)(d1_ + 1024) = pack8(S[6], S[7]);                               \
  } while (0)

#define KK(RB, KKV)                                                           \
  do {                                                                        \
    _Pragma("unroll") for (int mi = 0; mi < 8; ++mi)                          \
        av[mi] = *(const short8*)((RB) +                                      \
            (((wm * 8 + mi) * 2 + (KKV)) << 10) + rdo);                       \
    _Pragma("unroll") for (int pp = 0; pp < 4; ++pp)                          \
        bv[pp] = *(const short8*)((RB) + 32768 +                              \
            (((wn * 4 + pp) * 2 + (KKV)) << 10) + rdo);                       \
    __builtin_amdgcn_s_setprio(1);                                            \
    _Pragma("unroll") for (int mi = 0; mi < 8; ++mi)                          \
        _Pragma("unroll") for (int pp = 0; pp < 4; ++pp)                      \
            acc[mi][pp] = __builtin_amdgcn_mfma_f32_16x16x32_bf16(            \
                av[mi], bv[pp], acc[mi][pp], 0, 0, 0);                        \
    __builtin_amdgcn_s_setprio(0);                                            \
  } while (0)

#define PRO_WRITE(TT, ROFF)                                                   \
  do {                                                                        \
    short8 a_ = pack8(TT[0], TT[1]);                                          \
    short8 b_ = pack8(TT[2], TT[3]);                                          \
    char* d_ = smem + (ROFF) + wfrag;                                         \
    *(short8*)d_ = a_;                                                        \
    *(short8*)(d_ + 1024) = b_;                                               \
  } while (0)

__global__ __launch_bounds__(512, 2)
void ens_mlp_kernel(const float* __restrict__ X,
                    const float* __restrict__ W1,
                    const float* __restrict__ B1,
                    const float* __restrict__ W2,
                    const float* __restrict__ B2,
                    float* __restrict__ out)
{
    extern __shared__ char smem[];
    const int t    = threadIdx.x;
    const int lane = t & 63;
    const int wv   = t >> 6;
    const int wm   = wv >> 2;     // 0..1
    const int wn   = wv & 3;      // 0..3

    // XCD-aware decode: 8 blocks of the same km adjacent on one XCD.
    const int bb  = blockIdx.x;
    const int xcd = bb & 7;
    const int j   = bb >> 3;
    const int km  = xcd * 64 + (j >> 3);   // 0..511
    const int sub = j & 7;
    const int mt  = sub >> 1;              // 0..3 (256-row batch tile)
    const int nt  = sub & 1;               // 0..1 (256-col n half)

    const float* __restrict__ W1k = W1 + (size_t)km * (512 * 512);

    // staging identity: thread handles rows {lr, lr+128}, k-octs {c, c+4}
    const int lr = t >> 2;                 // 0..127
    const int c  = t & 3;
    const float* As = X   + (size_t)(mt * 256 + lr) * 512 + c * 8;
    const float* Bs = W1k + (size_t)(nt * 256 + lr) * 512 + c * 8;
    const int wfrag = ((lr >> 4) << 11) + (swz4((c << 4) | (lr & 15)) << 4);
    const int rdo   = swz4(lane) << 4;     // fragment read offset (logical=lane)

    // ---- prologue: stage tile 0 (counted drains) ----
    {
        f32x4 t0[4], t1[4], t2[4], t3[4];
        const float* q;
        q = As;          t0[0]=*(const f32x4*)q; t0[1]=*(const f32x4*)(q+4); t0[2]=*(const f32x4*)(q+32); t0[3]=*(const f32x4*)(q+36);
        q = As + 65536;  t1[0]=*(const f32x4*)q; t1[1]=*(const f32x4*)(q+4); t1[2]=*(const f32x4*)(q+32); t1[3]=*(const f32x4*)(q+36);
        q = Bs;          t2[0]=*(const f32x4*)q; t2[1]=*(const f32x4*)(q+4); t2[2]=*(const f32x4*)(q+32); t2[3]=*(const f32x4*)(q+36);
        q = Bs + 65536;  t3[0]=*(const f32x4*)q; t3[1]=*(const f32x4*)(q+4); t3[2]=*(const f32x4*)(q+32); t3[3]=*(const f32x4*)(q+36);
        asm volatile("s_waitcnt vmcnt(12)" ::: "memory"); PRO_WRITE(t0, 0);
        asm volatile("s_waitcnt vmcnt(8)"  ::: "memory"); PRO_WRITE(t1, 16384);
        asm volatile("s_waitcnt vmcnt(4)"  ::: "memory"); PRO_WRITE(t2, 32768);
        asm volatile("s_waitcnt vmcnt(0)"  ::: "memory"); PRO_WRITE(t3, 49152);
        asm volatile("s_waitcnt lgkmcnt(0)" ::: "memory");
        __builtin_amdgcn_sched_barrier(0);
        __builtin_amdgcn_s_barrier();
    }

    f32x4 acc[8][4];
#pragma unroll
    for (int i = 0; i < 8; ++i)
#pragma unroll
        for (int p = 0; p < 4; ++p)
            acc[i][p] = (f32x4)0.0f;

    short8 av[8], bv[4];
    f32x4 sS[8];   // single staging set, reused for B then A batch

#pragma unroll 1
    for (int kt = 0; kt < 7; ++kt) {
        const char* rb = smem + (kt & 1) * 65536;
        char* wb       = smem + ((kt + 1) & 1) * 65536;

        ISSUE(sS, Bs, kt + 1);                 // W1 batch for next tile
        KK(rb, 0);                             // 12 ds_read + 32 MFMA
        asm volatile("s_waitcnt vmcnt(0)" ::: "memory");
        WRITEB(sS, wb, 32768);                 // B -> other buffer
        ISSUE(sS, As, kt + 1);                 // X batch for next tile
        KK(rb, 1);
        asm volatile("s_waitcnt vmcnt(0)" ::: "memory");
        WRITEB(sS, wb, 0);                     // A -> other buffer
        asm volatile("s_waitcnt lgkmcnt(0)" ::: "memory");
        __builtin_amdgcn_sched_barrier(0);
        __builtin_amdgcn_s_barrier();
    }
    {   // kt = 7: compute only
        const char* rb = smem + 65536;
        KK(rb, 0);
        KK(rb, 1);
    }

    // ---- fused epilogue: partial over this block's 256 n-cols ----
    const int nc = lane & 15;
    const int kq = lane >> 4;
    float b1v[4], w2v[4];
#pragma unroll
    for (int pp = 0; pp < 4; ++pp) {
        int n = nt * 256 + (wn * 4 + pp) * 16 + nc;
        b1v[pp] = B1[km * 512 + n];
        w2v[pp] = W2[km * 512 + n];
    }

    float* lout = (float*)smem;   // buf0 region; tile7 read buf1 -> no clash
#pragma unroll
    for (int i = 0; i < 8; ++i) {
#pragma unroll
        for (int r = 0; r < 4; ++r) {
            float s = 0.f;
#pragma unroll
            for (int pp = 0; pp < 4; ++pp) {
                float h = acc[i][pp][r] + b1v[pp];
                h = h > 0.f ? h : 0.f;
                s += h * w2v[pp];
            }
#pragma unroll
            for (int d = 1; d < 16; d <<= 1)
                s += __shfl_xor(s, d, 64);
            if (nc == 0) {
                int row = wm * 128 + i * 16 + kq * 4 + r;
                lout[row * 4 + wn] = s;
            }
        }
    }
    __syncthreads();
    if (t < 256) {
        float s = lout[t * 4 + 0] + lout[t * 4 + 1] + lout[t * 4 + 2] + lout[t * 4 + 3];
        if (nt == 0) s += B2[km];
        int b = mt * 256 + t;
        // out[b, e, o] with k = o*E + e  ->  flat b*512 + (km%8)*64 + (km/8)
        atomicAdd(out + (size_t)b * 512 + (km & 7) * 64 + (km >> 3), s);
    }
}

extern "C" void kernel_launch(void* const* d_in, const int* in_sizes, int n_in,
                              void* d_out, int out_size, void* d_ws, size_t ws_size,
                              hipStream_t stream) {
    const float* X  = (const float*)d_in[0];
    const float* W1 = (const float*)d_in[1];
    const float* B1 = (const float*)d_in[2];
    const float* W2 = (const float*)d_in[3];
    const float* B2 = (const float*)d_in[4];
    float* out = (float*)d_out;

    hipMemsetAsync(out, 0, (size_t)out_size * sizeof(float), stream);
    ens_mlp_kernel<<<dim3(4096), dim3(512), 131072, stream>>>(X, W1, B1, W2, B2, out);
}